// Round 13
// baseline (301.114 us; speedup 1.0000x reference)
//
#include <hip/hip_runtime.h>
#include <cstdint>
#include <cstddef>

#define NN      10000
#define NE      320000
#define FINF    2
#define HIDN    64
#define OUTN    16
#define BBATCH  4
#define TSTEPS  12
#define NBROWS  (NN * BBATCH)                    // 40000 (n-major, row = n*B + b)
#define XTN     (TSTEPS * NN * BBATCH * FINF)    // 960000
#define CAP     96                               // bucket capacity; P(deg>96) ~ 1e-18
#define NBLK    (NN / 16)                        // 625 blocks
#define GT      (NBLK * 256)                     // 160000 grid threads

typedef _Float16 v8h __attribute__((ext_vector_type(8)));
typedef _Float16 v2h __attribute__((ext_vector_type(2)));
typedef float    v4f __attribute__((ext_vector_type(4)));

// R16 (resubmit #3 — R10/R11/R12 benches were broker timeouts, never measured).
// Fused mega-kernel WITHOUT hipLaunchCooperativeKernel.
// R15 (cooperative) FAILED correctness with absmax 1.08e-01 == max|ref| —
// the all-zero-output signature. Prime suspect: cooperative launch under the
// harness's graph capture silently failing (rigor.md tripwire); second
// suspect: cg::grid.sync() agent-scope semantics across 8 non-coherent L2s.
// This version fixes both: normal <<<625,256>>> launch + MANUAL grid barrier
// with explicit agent-scope release (threadfence -> L2 writeback) and
// acquire (__hip_atomic_load AGENT -> L1/L2 invalidate).
// Deadlock-safety: launch_bounds(256,3) => VGPR<=168 (we use ~84) and
// LDS 39424B => 4 blk/CU by LDS => 3 blk/CU guaranteed => 768 slots >= 625
// blocks all co-resident; spin barrier cannot deadlock.
// cnt/degf/bar zeroed by ONE hipMemsetAsync (graph-capture-proven path).
__device__ __forceinline__ float fsigmoid(float x) {
    // 1/(1+e^-x) = rcp(1 + exp2(-x*log2e)) — native 3-op path (R14 win)
    return __builtin_amdgcn_rcpf(1.0f + __builtin_amdgcn_exp2f(-1.442695041f * x));
}

extern "C" __global__ __launch_bounds__(256, 3)
void mega_kernel(const float* __restrict__ x,
                 const int* __restrict__ src, const int* __restrict__ dst,
                 const float* __restrict__ ew,
                 int* __restrict__ cnt, float* __restrict__ degf,
                 int2* __restrict__ bucket, _Float16* __restrict__ xAll,
                 const float* __restrict__ Wz, const float* __restrict__ bz,
                 const float* __restrict__ Wr, const float* __restrict__ br,
                 const float* __restrict__ Wh, const float* __restrict__ bh,
                 const float* __restrict__ Lz, const float* __restrict__ Lz_b,
                 const float* __restrict__ Lr, const float* __restrict__ Lr_b,
                 const float* __restrict__ Lh, const float* __restrict__ Lh_b,
                 const float* __restrict__ linw, const float* __restrict__ linb,
                 float* __restrict__ PP, int* __restrict__ bar,
                 float* __restrict__ out) {
    __shared__ _Float16 WTH[64 * 72 + 32];      // H~: [n][k<64 | 64..66 init], pad
    __shared__ _Float16 WIZR[2 * 64 * 8 + 32];  // Z,R init: [g][n][0..7], pad
    __shared__ _Float16 Hm[4][16 * 72];         // per-wave H [row][col^swz]
    __shared__ float    aggL[16 * 96];          // block's 16 nodes x 96 (fp32)
    __shared__ int      s_src[16 * CAP];        // staged edge sources
    __shared__ float    s_c[16 * CAP];          // staged edge coefficients
    __shared__ int      s_cnt[16];

    const int tid  = threadIdx.x;
    const int bid  = blockIdx.x;
    const int gtid = bid * 256 + tid;            // 0..159999

    // ================= stage 1: scatter + transpose + fold =================
    // (cnt/degf/bar pre-zeroed by hipMemsetAsync on the same stream)
    // transpose: thread per node n; xAll[n][96] fp16, j = t*8 + b*2 + f
    if (gtid < NN) {
        const int n = gtid;
        v8h* xo = (v8h*)(xAll + (size_t)n * 96);
        v8h vv[TSTEPS];
        #pragma unroll
        for (int b = 0; b < BBATCH; ++b) {
            const v4f* xp4 = (const v4f*)(x + ((size_t)b * NN + n) * 24);
            v4f c0 = xp4[0], c1 = xp4[1], c2 = xp4[2];
            v4f c3 = xp4[3], c4 = xp4[4], c5 = xp4[5];
            float f0[TSTEPS] = {c0.x, c0.y, c0.z, c0.w, c1.x, c1.y, c1.z, c1.w,
                                c2.x, c2.y, c2.z, c2.w};
            float f1[TSTEPS] = {c3.x, c3.y, c3.z, c3.w, c4.x, c4.y, c4.z, c4.w,
                                c5.x, c5.y, c5.z, c5.w};
            #pragma unroll
            for (int t = 0; t < TSTEPS; ++t) {
                vv[t][b * 2]     = (_Float16)f0[t];
                vv[t][b * 2 + 1] = (_Float16)f1[t];
            }
        }
        #pragma unroll
        for (int t = 0; t < TSTEPS; ++t) xo[t] = vv[t];
    }
    // bucket scatter by dst + weighted degree (2 edges per thread)
    #pragma unroll
    for (int e = gtid; e < NE; e += GT) {
        int d = dst[e];
        int s = src[e];
        float wv = ew[e];
        int p = atomicAdd(&cnt[d], 1);           // device-scope by default
        if (p < CAP) {
            int2 rec;
            rec.x = s;
            rec.y = __float_as_int(wv);
            bucket[d * CAP + p] = rec;
        }
        atomicAdd(&degf[d], wv);
    }
    // parameter folding
    if (gtid < 13904) {
        const float* Lg[3]    = {Lz, Lr, Lh};
        const float* Lbias[3] = {Lz_b, Lr_b, Lh_b};
        const float* Wg[3]    = {Wz, Wr, Wh};
        const float* bg[3]    = {bz, br, bh};
        int i = gtid;
        if (i < 12288) {
            int g = i >> 12, rr = (i >> 6) & 63, j = i & 63;
            PP[i] = Lg[g][(64 + rr) * 64 + j];
        } else if (i < 12672) {
            int i2 = i - 12288;
            int g = i2 >> 7, f = (i2 >> 6) & 1, j = i2 & 63;
            float s = 0.f;
            for (int k = 0; k < 64; ++k) s = fmaf(Wg[g][f * 64 + k], Lg[g][k * 64 + j], s);
            PP[i] = s;
        } else if (i < 12864) {
            int i3 = i - 12672;
            int g = i3 >> 6, j = i3 & 63;
            float s = Lbias[g][j];
            for (int k = 0; k < 64; ++k) s = fmaf(bg[g][k], Lg[g][k * 64 + j], s);
            PP[i] = s;
        } else if (i < 13888) {
            PP[i] = linw[i - 12864];
        } else {
            PP[i] = linb[i - 13888];
        }
    }

    // ============ manual grid barrier (agent-scope release/acquire) ==========
    __syncthreads();                              // block's stage-1 work issued
    if (tid == 0) {
        __threadfence();                          // agent release: L2 writeback
        __hip_atomic_fetch_add(bar, 1, __ATOMIC_ACQ_REL, __HIP_MEMORY_SCOPE_AGENT);
        while (__hip_atomic_load(bar, __ATOMIC_ACQUIRE, __HIP_MEMORY_SCOPE_AGENT) < NBLK) {
            __builtin_amdgcn_s_sleep(8);          // polite spin
        }
        // acquire load above emits the L1/L2 invalidate for this CU/XCD
    }
    __syncthreads();                              // whole block proceeds

    // ================= stage 2: fused aggregate + recurrent GRU =============
    const int w   = tid >> 6;
    const int l   = tid & 63;
    const int m   = l & 15;          // A row / B,C col within 16x16 tile
    const int q   = l >> 4;          // quad: A k-group, C row-group
    const int n0  = bid * 16 + w * 4 + q;   // lane's output node

    // ---- phase A: parallel edge staging (16 chains per node) ----
    {
        const int nl = tid >> 4;            // node 0..15
        const int u  = tid & 15;
        const int ng = bid * 16 + nl;
        const int c  = min(cnt[ng], CAP);
        if (u == 0) s_cnt[nl] = c;
        const float dn = rsqrtf(1.0f + degf[ng]);
        for (int i = u; i < c; i += 16) {
            int2 rec = bucket[ng * CAP + i];
            int s = rec.x;
            s_src[nl * CAP + i] = s;
            s_c[nl * CAP + i]   = __int_as_float(rec.y) * dn * rsqrtf(1.0f + degf[s]);
        }
    }

    // ---- stage H~ gate [n][k] + init cols 64..66 (overlaps phase A latency) ----
    for (int i = tid; i < 4096; i += 256) {
        int k = i >> 6, n = i & 63;
        WTH[n * 72 + k] = (_Float16)PP[8192 + i];
    }
    for (int i = tid; i < 64 * 8; i += 256) {
        int n = i >> 3, kk = i & 7;
        float v = 0.f;
        if (kk == 0)      v = PP[12288 + 2 * 128 + n];
        else if (kk == 1) v = PP[12288 + 2 * 128 + 64 + n];
        else if (kk == 2) v = PP[12672 + 2 * 64 + n];
        WTH[n * 72 + 64 + kk] = (_Float16)v;
    }
    for (int i = tid; i < 32; i += 256) WTH[64 * 72 + i] = (_Float16)0.f;
    // ---- stage Z,R init rows ----
    for (int i = tid; i < 2 * 64 * 8; i += 256) {
        int g = i >> 9, rem = i & 511, n = rem >> 3, kk = rem & 7;
        float v = 0.f;
        if (kk == 0)      v = PP[12288 + g * 128 + n];
        else if (kk == 1) v = PP[12288 + g * 128 + 64 + n];
        else if (kk == 2) v = PP[12672 + g * 64 + n];
        WIZR[(g * 64 + n) * 8 + kk] = (_Float16)v;
    }
    for (int i = tid; i < 32; i += 256) WIZR[1024 + i] = (_Float16)0.f;

    __syncthreads();   // phase A + weight staging visible

    // ---- phase B: throughput aggregation into aggL ----
    {
        const int nl = tid >> 4;
        const int u  = tid & 15;
        const int ng = bid * 16 + nl;
        const int c  = s_cnt[nl];
        const float dn = rsqrtf(1.0f + degf[ng]);   // L1-hot
        const v2h* x2 = (const v2h*)xAll;
        float acc[6];
        {
            v2h a = x2[(size_t)ng * 48 + u * 3];
            v2h b = x2[(size_t)ng * 48 + u * 3 + 1];
            v2h e = x2[(size_t)ng * 48 + u * 3 + 2];
            float c0 = dn * dn;
            acc[0] = c0 * (float)a.x; acc[1] = c0 * (float)a.y;
            acc[2] = c0 * (float)b.x; acc[3] = c0 * (float)b.y;
            acc[4] = c0 * (float)e.x; acc[5] = c0 * (float)e.y;
        }
        for (int i = 0; i < c; ++i) {
            int s    = s_src[nl * CAP + i];       // same-addr broadcast
            float cc = s_c[nl * CAP + i];
            v2h a = x2[(size_t)s * 48 + u * 3];
            v2h b = x2[(size_t)s * 48 + u * 3 + 1];
            v2h e = x2[(size_t)s * 48 + u * 3 + 2];
            acc[0] = fmaf(cc, (float)a.x, acc[0]);
            acc[1] = fmaf(cc, (float)a.y, acc[1]);
            acc[2] = fmaf(cc, (float)b.x, acc[2]);
            acc[3] = fmaf(cc, (float)b.y, acc[3]);
            acc[4] = fmaf(cc, (float)e.x, acc[4]);
            acc[5] = fmaf(cc, (float)e.y, acc[5]);
        }
        #pragma unroll
        for (int jj = 0; jj < 6; ++jj) aggL[nl * 96 + u * 6 + jj] = acc[jj];
    }

    // ---- Z, R gate B-fragments -> registers (loop-invariant) ----
    v8h BZ[4][2], BR[4][2];
    #pragma unroll
    for (int nt = 0; nt < 4; ++nt) {
        #pragma unroll
        for (int c = 0; c < 2; ++c) {
            #pragma unroll
            for (int i = 0; i < 8; ++i) {
                int k = c * 32 + q * 8 + i;
                BZ[nt][c][i] = (_Float16)PP[k * 64 + nt * 16 + m];
                BR[nt][c][i] = (_Float16)PP[4096 + k * 64 + nt * 16 + m];
            }
        }
    }
    // lin B-fragments + bias
    v8h linB0, linB1;
    #pragma unroll
    for (int i = 0; i < 8; ++i) {
        linB0[i] = (_Float16)PP[12864 + (q * 8 + i) * 16 + m];
        linB1[i] = (_Float16)PP[12864 + (32 + q * 8 + i) * 16 + m];
    }
    const float linbv = PP[13888 + m];

    __syncthreads();   // aggL visible

    _Float16* __restrict__ Hw = &Hm[w][0];
    const int wsw = (q & 2) << 3;                  // write column swizzle
    const _Float16* __restrict__ Ard = Hw + m * 72 + ((q ^ ((m >> 2) & 2)) * 8);
    // aI source: local row w*16+m -> node-local (w*4 + (m>>2)), b = m&3
    const int aggBase = (w * 4 + (m >> 2)) * 96 + (m & 3) * 2;

    float Hold[4][4];                 // fp32 H master, C-layout [ntile][reg]
    #pragma unroll
    for (int nt = 0; nt < 4; ++nt)
        #pragma unroll
        for (int r = 0; r < 4; ++r) Hold[nt][r] = 0.f;
    v8h aH0{}, aH1{};                 // A-fragments of H (zero at t=0)

    const v4f zeroc = {0.f, 0.f, 0.f, 0.f};
    // out base for this lane (t=0, r=0); strides: +NN*16 per t, +T*NN*16 per r
    float* __restrict__ op = out + (size_t)n0 * 16 + m;

    for (int t = 0; t < TSTEPS; ++t) {
        // init A-fragment: [a0, a1, 1, 0...] on q=0 lanes, else 0
        v8h aI{};
        if (q == 0) {
            const float2 av = *(const float2*)&aggL[aggBase + t * 8];
            aI[0] = (_Float16)av.x;
            aI[1] = (_Float16)av.y;
            aI[2] = (_Float16)1.0f;
        }

        // ---- Z, R: init (LDS B) + 2 register-B MFMAs per n-tile ----
        v4f accZ[4], accR[4];
        #pragma unroll
        for (int nt = 0; nt < 4; ++nt) {
            const v8h bIz = *(const v8h*)&WIZR[(0 * 64 + nt * 16 + m) * 8 + q * 8];
            const v8h bIr = *(const v8h*)&WIZR[(1 * 64 + nt * 16 + m) * 8 + q * 8];
            accZ[nt] = __builtin_amdgcn_mfma_f32_16x16x32_f16(aI,  bIz,       zeroc,    0, 0, 0);
            accZ[nt] = __builtin_amdgcn_mfma_f32_16x16x32_f16(aH0, BZ[nt][0], accZ[nt], 0, 0, 0);
            accZ[nt] = __builtin_amdgcn_mfma_f32_16x16x32_f16(aH1, BZ[nt][1], accZ[nt], 0, 0, 0);
            accR[nt] = __builtin_amdgcn_mfma_f32_16x16x32_f16(aI,  bIr,       zeroc,    0, 0, 0);
            accR[nt] = __builtin_amdgcn_mfma_f32_16x16x32_f16(aH0, BR[nt][0], accR[nt], 0, 0, 0);
            accR[nt] = __builtin_amdgcn_mfma_f32_16x16x32_f16(aH1, BR[nt][1], accR[nt], 0, 0, 0);
        }

        // ---- gates; write HR (fp16, swizzled) for H~'s A-operand ----
        float Z[4][4];
        #pragma unroll
        for (int nt = 0; nt < 4; ++nt) {
            #pragma unroll
            for (int r = 0; r < 4; ++r) {
                Z[nt][r] = fsigmoid(accZ[nt][r]);
                float hr = Hold[nt][r] * fsigmoid(accR[nt][r]);
                Hw[(q * 4 + r) * 72 + ((nt * 16 + m) ^ wsw)] = (_Float16)hr;
            }
        }
        __threadfence_block();   // intra-wave LDS visibility
        const v8h aP0 = *(const v8h*)Ard;
        const v8h aP1 = *(const v8h*)(Ard + 32);

        // ---- H_tilde (B from LDS WTH) ----
        v4f accH[4];
        #pragma unroll
        for (int nt = 0; nt < 4; ++nt) {
            const _Float16* bh = &WTH[(nt * 16 + m) * 72 + q * 8];
            accH[nt] = __builtin_amdgcn_mfma_f32_16x16x32_f16(aI,  *(const v8h*)(bh + 64), zeroc,    0, 0, 0);
            accH[nt] = __builtin_amdgcn_mfma_f32_16x16x32_f16(aP0, *(const v8h*)bh,        accH[nt], 0, 0, 0);
            accH[nt] = __builtin_amdgcn_mfma_f32_16x16x32_f16(aP1, *(const v8h*)(bh + 32), accH[nt], 0, 0, 0);
        }

        // ---- combine; update register H; write Hn (swizzled) ----
        #pragma unroll
        for (int nt = 0; nt < 4; ++nt) {
            #pragma unroll
            for (int r = 0; r < 4; ++r) {
                float ht = fmaf(2.0f, fsigmoid(2.0f * accH[nt][r]), -1.0f);   // tanh
                float hn = Z[nt][r] * Hold[nt][r] + (1.f - Z[nt][r]) * ht;
                Hold[nt][r] = hn;
                Hw[(q * 4 + r) * 72 + ((nt * 16 + m) ^ wsw)] = (_Float16)hn;
            }
        }
        __threadfence_block();
        aH0 = *(const v8h*)Ard;          // reused next step's Z/R
        aH1 = *(const v8h*)(Ard + 32);

        // ---- output: relu(Hn) @ lin + lin_b ----
        const v8h zz{};
        v8h r0 = __builtin_elementwise_max(aH0, zz);
        v8h r1 = __builtin_elementwise_max(aH1, zz);
        v4f accO = {linbv, linbv, linbv, linbv};
        accO = __builtin_amdgcn_mfma_f32_16x16x32_f16(r0, linB0, accO, 0, 0, 0);
        accO = __builtin_amdgcn_mfma_f32_16x16x32_f16(r1, linB1, accO, 0, 0, 0);
        #pragma unroll
        for (int r = 0; r < 4; ++r)      // C row q*4+r -> (n0, b=r), col m
            op[(size_t)r * (TSTEPS * NN * 16)] = accO[r];
        op += NN * 16;                   // advance t
    }
}

// ---------------- launch ----------------

extern "C" void kernel_launch(void* const* d_in, const int* in_sizes, int n_in,
                              void* d_out, int out_size, void* d_ws, size_t ws_size,
                              hipStream_t stream) {
    const float* x   = (const float*)d_in[0];
    const int*   ei  = (const int*)d_in[1];
    const float* ew  = (const float*)d_in[2];
    const float* Wz  = (const float*)d_in[3];
    const float* bz  = (const float*)d_in[4];
    const float* Wr  = (const float*)d_in[5];
    const float* br  = (const float*)d_in[6];
    const float* Wh  = (const float*)d_in[7];
    const float* bh  = (const float*)d_in[8];
    const float* Lz  = (const float*)d_in[9];
    const float* Lz_b= (const float*)d_in[10];
    const float* Lr  = (const float*)d_in[11];
    const float* Lr_b= (const float*)d_in[12];
    const float* Lh  = (const float*)d_in[13];
    const float* Lh_b= (const float*)d_in[14];
    const float* lw  = (const float*)d_in[15];
    const float* lb  = (const float*)d_in[16];
    float* out = (float*)d_out;

    char* ws = (char*)d_ws;
    size_t off = 0;
    auto alloc = [&](size_t bytes) -> char* {
        char* p = ws + off;
        off += (bytes + 15) & ~(size_t)15;
        return p;
    };
    _Float16* xAll = (_Float16*)alloc((size_t)XTN * 2);
    float* PP      = (float*)alloc(13904 * 4);
    int2*  bucket  = (int2*) alloc((size_t)NN * CAP * 8);
    int*   cnt     = (int*)  alloc(NN * 4);   // cnt, degf, bar adjacent:
    float* degf    = (float*)alloc(NN * 4);   //   one memset zeroes all three
    int*   bar     = (int*)  alloc(16);

    const int* srcp = ei;
    const int* dstp = ei + NE;

    hipMemsetAsync(cnt, 0, 2 * NN * sizeof(int) + 16, stream);   // cnt+degf+bar
    mega_kernel<<<NBLK, 256, 0, stream>>>(x, srcp, dstp, ew, cnt, degf,
                                          bucket, xAll,
                                          Wz, bz, Wr, br, Wh, bh,
                                          Lz, Lz_b, Lr, Lr_b, Lh, Lh_b,
                                          lw, lb, PP, bar, out);
}

// Round 17
// 183.067 us; speedup vs baseline: 1.6448x; 1.6448x over previous
//
#include <hip/hip_runtime.h>
#include <cstdint>
#include <cstddef>

#define NN      10000
#define NE      320000
#define FINF    2
#define HIDN    64
#define OUTN    16
#define BBATCH  4
#define TSTEPS  12
#define NBROWS  (NN * BBATCH)                    // 40000 (n-major, row = n*B + b)
#define XTN     (TSTEPS * NN * BBATCH * FINF)    // 960000
#define CAP     96                               // bucket capacity; P(deg>96) ~ 1e-18

typedef _Float16 v8h __attribute__((ext_vector_type(8)));
typedef _Float16 v2h __attribute__((ext_vector_type(2)));
typedef float    v4f __attribute__((ext_vector_type(4)));

// R17 (resubmit #3 — three consecutive broker timeouts, never measured).
// Revert to the R14 3-launch chassis (best measured: 193.8us e2e,
// fused 60.7us) after BOTH fusion attempts failed:
//   R15 cooperative: correctness fail (silent launch failure under graph
//       capture -> all-zero out).
//   R16 manual spin barrier: correct but +110us GPU (ACQUIRE polls at AGENT
//       scope invalidate L1/L2 under blocks still in stage-1; 625 spinners
//       ping-pong one line across 8 L2s). Fixed harness overhead measured
//       ~65-70us -> the old "dispatch boundary" theory is refuted.
// New content cut — NORM PRE-FOLD: agg[d] = dinv[d]*(sum_e w_e*xs[s] + xs[d])
// with xs[n] = dinv[n]*x[n]. So:
//   k1 scatter: bucket + cnt only (NO degf float atomics; 2 random ops/edge
//      instead of 3) + param fold.
//   k2 prep: per node, deg = sum of own-bucket w (coalesced reads, no
//      atomics), dinv = rsqrt(1+deg), transpose x -> xs (scaled) fp16.
//   k3 fused: phase A = pure bucket->LDS copy (no degf gathers, no rsqrt);
//      phase B: cc = w, init acc = xs row, final aggL = acc*dn.
__device__ __forceinline__ float fsigmoid(float x) {
    // 1/(1+e^-x) = rcp(1 + exp2(-x*log2e)) — native 3-op path (R14 win)
    return __builtin_amdgcn_rcpf(1.0f + __builtin_amdgcn_exp2f(-1.442695041f * x));
}

// ---------------- k1: edge scatter + parameter fold ----------------
extern "C" __global__ void scatter_kernel(const int* __restrict__ src,
                             const int* __restrict__ dst,
                             const float* __restrict__ ew,
                             int* __restrict__ cnt, int2* __restrict__ bucket,
                             const float* __restrict__ Wz, const float* __restrict__ bz,
                             const float* __restrict__ Wr, const float* __restrict__ br,
                             const float* __restrict__ Wh, const float* __restrict__ bh,
                             const float* __restrict__ Lz, const float* __restrict__ Lz_b,
                             const float* __restrict__ Lr, const float* __restrict__ Lr_b,
                             const float* __restrict__ Lh, const float* __restrict__ Lh_b,
                             const float* __restrict__ linw, const float* __restrict__ linb,
                             float* __restrict__ PP) {
    int idx = blockIdx.x * 256 + threadIdx.x;
    if (idx < NE) {
        int d = dst[idx];
        int s = src[idx];
        float w = ew[idx];
        int p = atomicAdd(&cnt[d], 1);
        if (p < CAP) {
            int2 rec;
            rec.x = s;
            rec.y = __float_as_int(w);
            bucket[d * CAP + p] = rec;
        }
    }
    if (idx < 13904) {
        const float* Lg[3]    = {Lz, Lr, Lh};
        const float* Lbias[3] = {Lz_b, Lr_b, Lh_b};
        const float* Wg[3]    = {Wz, Wr, Wh};
        const float* bg[3]    = {bz, br, bh};
        int i = idx;
        if (i < 12288) {
            int g = i >> 12, rr = (i >> 6) & 63, j = i & 63;
            PP[i] = Lg[g][(64 + rr) * 64 + j];
        } else if (i < 12672) {
            int i2 = i - 12288;
            int g = i2 >> 7, f = (i2 >> 6) & 1, j = i2 & 63;
            float s = 0.f;
            for (int k = 0; k < 64; ++k) s = fmaf(Wg[g][f * 64 + k], Lg[g][k * 64 + j], s);
            PP[i] = s;
        } else if (i < 12864) {
            int i3 = i - 12672;
            int g = i3 >> 6, j = i3 & 63;
            float s = Lbias[g][j];
            for (int k = 0; k < 64; ++k) s = fmaf(bg[g][k], Lg[g][k * 64 + j], s);
            PP[i] = s;
        } else if (i < 13888) {
            PP[i] = linw[i - 12864];
        } else {
            PP[i] = linb[i - 13888];
        }
    }
}

// ---------------- k2: degree from bucket + dinv + scaled transpose --------
// Thread per node: deg = sum of own-bucket weights (768B coalesced run per
// thread, consecutive threads consecutive runs), dinv = rsqrt(1+deg), then
// the R14 transpose with each value scaled by dinv -> xs fp16.
extern "C" __global__ void prep_kernel(const float* __restrict__ x,
                                       const int* __restrict__ cnt,
                                       const int2* __restrict__ bucket,
                                       float* __restrict__ dinv,
                                       _Float16* __restrict__ xAll) {
    int n = blockIdx.x * 256 + threadIdx.x;
    if (n >= NN) return;
    const int c = min(cnt[n], CAP);
    float deg = 0.f;
    const int2* bp = bucket + (size_t)n * CAP;
    for (int i = 0; i < c; ++i) deg += __int_as_float(bp[i].y);
    const float dv = rsqrtf(1.0f + deg);
    dinv[n] = dv;

    v8h* xo = (v8h*)(xAll + (size_t)n * 96);
    v8h vv[TSTEPS];
    #pragma unroll
    for (int b = 0; b < BBATCH; ++b) {
        const v4f* xp4 = (const v4f*)(x + ((size_t)b * NN + n) * 24);
        v4f c0 = xp4[0], c1 = xp4[1], c2 = xp4[2];
        v4f c3 = xp4[3], c4 = xp4[4], c5 = xp4[5];
        float f0[TSTEPS] = {c0.x, c0.y, c0.z, c0.w, c1.x, c1.y, c1.z, c1.w,
                            c2.x, c2.y, c2.z, c2.w};
        float f1[TSTEPS] = {c3.x, c3.y, c3.z, c3.w, c4.x, c4.y, c4.z, c4.w,
                            c5.x, c5.y, c5.z, c5.w};
        #pragma unroll
        for (int t = 0; t < TSTEPS; ++t) {
            vv[t][b * 2]     = (_Float16)(f0[t] * dv);
            vv[t][b * 2 + 1] = (_Float16)(f1[t] * dv);
        }
    }
    #pragma unroll
    for (int t = 0; t < TSTEPS; ++t) xo[t] = vv[t];
}

// ---------------- k3: fused aggregate + recurrent GRU ----------------
// R14 body; phase A = pure bucket copy, phase B: cc = w, init = xs row,
// final aggL = acc*dn.
extern "C" __global__ __launch_bounds__(256, 3)
void fused_kernel(const _Float16* __restrict__ xAll, const int2* __restrict__ bucket,
                  const int* __restrict__ cnt, const float* __restrict__ dinv,
                  const float* __restrict__ PP, float* __restrict__ out) {
    __shared__ _Float16 WTH[64 * 72 + 32];      // H~: [n][k<64 | 64..66 init], pad
    __shared__ _Float16 WIZR[2 * 64 * 8 + 32];  // Z,R init: [g][n][0..7], pad
    __shared__ _Float16 Hm[4][16 * 72];         // per-wave H [row][col^swz]
    __shared__ float    aggL[16 * 96];          // block's 16 nodes x 96 (fp32)
    __shared__ int      s_src[16 * CAP];        // staged edge sources
    __shared__ float    s_c[16 * CAP];          // staged edge weights
    __shared__ int      s_cnt[16];
    const int tid = threadIdx.x;
    const int w   = tid >> 6;
    const int l   = tid & 63;
    const int m   = l & 15;          // A row / B,C col within 16x16 tile
    const int q   = l >> 4;          // quad: A k-group, C row-group
    const int n0  = blockIdx.x * 16 + w * 4 + q;   // lane's output node

    // ---- phase A: bucket -> LDS copy (16 lanes per node) ----
    {
        const int nl = tid >> 4;            // node 0..15
        const int u  = tid & 15;
        const int ng = blockIdx.x * 16 + nl;
        const int c  = min(cnt[ng], CAP);
        if (u == 0) s_cnt[nl] = c;
        for (int i = u; i < c; i += 16) {
            int2 rec = bucket[ng * CAP + i];
            s_src[nl * CAP + i] = rec.x;
            s_c[nl * CAP + i]   = __int_as_float(rec.y);
        }
    }

    // ---- stage H~ gate [n][k] + init cols 64..66 (overlaps phase A latency) ----
    for (int i = tid; i < 4096; i += 256) {
        int k = i >> 6, n = i & 63;
        WTH[n * 72 + k] = (_Float16)PP[8192 + i];
    }
    for (int i = tid; i < 64 * 8; i += 256) {
        int n = i >> 3, kk = i & 7;
        float v = 0.f;
        if (kk == 0)      v = PP[12288 + 2 * 128 + n];
        else if (kk == 1) v = PP[12288 + 2 * 128 + 64 + n];
        else if (kk == 2) v = PP[12672 + 2 * 64 + n];
        WTH[n * 72 + 64 + kk] = (_Float16)v;
    }
    for (int i = tid; i < 32; i += 256) WTH[64 * 72 + i] = (_Float16)0.f;
    // ---- stage Z,R init rows ----
    for (int i = tid; i < 2 * 64 * 8; i += 256) {
        int g = i >> 9, rem = i & 511, n = rem >> 3, kk = rem & 7;
        float v = 0.f;
        if (kk == 0)      v = PP[12288 + g * 128 + n];
        else if (kk == 1) v = PP[12288 + g * 128 + 64 + n];
        else if (kk == 2) v = PP[12672 + g * 64 + n];
        WIZR[(g * 64 + n) * 8 + kk] = (_Float16)v;
    }
    for (int i = tid; i < 32; i += 256) WIZR[1024 + i] = (_Float16)0.f;

    __syncthreads();   // phase A + weight staging visible

    // ---- phase B: throughput aggregation into aggL ----
    {
        const int nl = tid >> 4;
        const int u  = tid & 15;
        const int ng = blockIdx.x * 16 + nl;
        const int c  = s_cnt[nl];
        const float dn = dinv[ng];                  // L1-hot
        const v2h* x2 = (const v2h*)xAll;
        float acc[6];
        {
            v2h a = x2[(size_t)ng * 48 + u * 3];
            v2h b = x2[(size_t)ng * 48 + u * 3 + 1];
            v2h e = x2[(size_t)ng * 48 + u * 3 + 2];
            acc[0] = (float)a.x; acc[1] = (float)a.y;
            acc[2] = (float)b.x; acc[3] = (float)b.y;
            acc[4] = (float)e.x; acc[5] = (float)e.y;
        }
        for (int i = 0; i < c; ++i) {
            int s    = s_src[nl * CAP + i];       // same-addr broadcast
            float cc = s_c[nl * CAP + i];
            v2h a = x2[(size_t)s * 48 + u * 3];
            v2h b = x2[(size_t)s * 48 + u * 3 + 1];
            v2h e = x2[(size_t)s * 48 + u * 3 + 2];
            acc[0] = fmaf(cc, (float)a.x, acc[0]);
            acc[1] = fmaf(cc, (float)a.y, acc[1]);
            acc[2] = fmaf(cc, (float)b.x, acc[2]);
            acc[3] = fmaf(cc, (float)b.y, acc[3]);
            acc[4] = fmaf(cc, (float)e.x, acc[4]);
            acc[5] = fmaf(cc, (float)e.y, acc[5]);
        }
        #pragma unroll
        for (int jj = 0; jj < 6; ++jj) aggL[nl * 96 + u * 6 + jj] = acc[jj] * dn;
    }

    // ---- Z, R gate B-fragments -> registers (loop-invariant) ----
    v8h BZ[4][2], BR[4][2];
    #pragma unroll
    for (int nt = 0; nt < 4; ++nt) {
        #pragma unroll
        for (int c = 0; c < 2; ++c) {
            #pragma unroll
            for (int i = 0; i < 8; ++i) {
                int k = c * 32 + q * 8 + i;
                BZ[nt][c][i] = (_Float16)PP[k * 64 + nt * 16 + m];
                BR[nt][c][i] = (_Float16)PP[4096 + k * 64 + nt * 16 + m];
            }
        }
    }
    // lin B-fragments + bias
    v8h linB0, linB1;
    #pragma unroll
    for (int i = 0; i < 8; ++i) {
        linB0[i] = (_Float16)PP[12864 + (q * 8 + i) * 16 + m];
        linB1[i] = (_Float16)PP[12864 + (32 + q * 8 + i) * 16 + m];
    }
    const float linbv = PP[13888 + m];

    __syncthreads();   // aggL visible

    _Float16* __restrict__ Hw = &Hm[w][0];
    const int wsw = (q & 2) << 3;                  // write column swizzle
    const _Float16* __restrict__ Ard = Hw + m * 72 + ((q ^ ((m >> 2) & 2)) * 8);
    // aI source: local row w*16+m -> node-local (w*4 + (m>>2)), b = m&3
    const int aggBase = (w * 4 + (m >> 2)) * 96 + (m & 3) * 2;

    float Hold[4][4];                 // fp32 H master, C-layout [ntile][reg]
    #pragma unroll
    for (int nt = 0; nt < 4; ++nt)
        #pragma unroll
        for (int r = 0; r < 4; ++r) Hold[nt][r] = 0.f;
    v8h aH0{}, aH1{};                 // A-fragments of H (zero at t=0)

    const v4f zeroc = {0.f, 0.f, 0.f, 0.f};
    // out base for this lane (t=0, r=0); strides: +NN*16 per t, +T*NN*16 per r
    float* __restrict__ op = out + (size_t)n0 * 16 + m;

    for (int t = 0; t < TSTEPS; ++t) {
        // init A-fragment: [a0, a1, 1, 0...] on q=0 lanes, else 0
        v8h aI{};
        if (q == 0) {
            const float2 av = *(const float2*)&aggL[aggBase + t * 8];
            aI[0] = (_Float16)av.x;
            aI[1] = (_Float16)av.y;
            aI[2] = (_Float16)1.0f;
        }

        // ---- Z, R: init (LDS B) + 2 register-B MFMAs per n-tile ----
        v4f accZ[4], accR[4];
        #pragma unroll
        for (int nt = 0; nt < 4; ++nt) {
            const v8h bIz = *(const v8h*)&WIZR[(0 * 64 + nt * 16 + m) * 8 + q * 8];
            const v8h bIr = *(const v8h*)&WIZR[(1 * 64 + nt * 16 + m) * 8 + q * 8];
            accZ[nt] = __builtin_amdgcn_mfma_f32_16x16x32_f16(aI,  bIz,       zeroc,    0, 0, 0);
            accZ[nt] = __builtin_amdgcn_mfma_f32_16x16x32_f16(aH0, BZ[nt][0], accZ[nt], 0, 0, 0);
            accZ[nt] = __builtin_amdgcn_mfma_f32_16x16x32_f16(aH1, BZ[nt][1], accZ[nt], 0, 0, 0);
            accR[nt] = __builtin_amdgcn_mfma_f32_16x16x32_f16(aI,  bIr,       zeroc,    0, 0, 0);
            accR[nt] = __builtin_amdgcn_mfma_f32_16x16x32_f16(aH0, BR[nt][0], accR[nt], 0, 0, 0);
            accR[nt] = __builtin_amdgcn_mfma_f32_16x16x32_f16(aH1, BR[nt][1], accR[nt], 0, 0, 0);
        }

        // ---- gates; write HR (fp16, swizzled) for H~'s A-operand ----
        float Z[4][4];
        #pragma unroll
        for (int nt = 0; nt < 4; ++nt) {
            #pragma unroll
            for (int r = 0; r < 4; ++r) {
                Z[nt][r] = fsigmoid(accZ[nt][r]);
                float hr = Hold[nt][r] * fsigmoid(accR[nt][r]);
                Hw[(q * 4 + r) * 72 + ((nt * 16 + m) ^ wsw)] = (_Float16)hr;
            }
        }
        __threadfence_block();   // intra-wave LDS visibility
        const v8h aP0 = *(const v8h*)Ard;
        const v8h aP1 = *(const v8h*)(Ard + 32);

        // ---- H_tilde (B from LDS WTH) ----
        v4f accH[4];
        #pragma unroll
        for (int nt = 0; nt < 4; ++nt) {
            const _Float16* bh = &WTH[(nt * 16 + m) * 72 + q * 8];
            accH[nt] = __builtin_amdgcn_mfma_f32_16x16x32_f16(aI,  *(const v8h*)(bh + 64), zeroc,    0, 0, 0);
            accH[nt] = __builtin_amdgcn_mfma_f32_16x16x32_f16(aP0, *(const v8h*)bh,        accH[nt], 0, 0, 0);
            accH[nt] = __builtin_amdgcn_mfma_f32_16x16x32_f16(aP1, *(const v8h*)(bh + 32), accH[nt], 0, 0, 0);
        }

        // ---- combine; update register H; write Hn (swizzled) ----
        #pragma unroll
        for (int nt = 0; nt < 4; ++nt) {
            #pragma unroll
            for (int r = 0; r < 4; ++r) {
                float ht = fmaf(2.0f, fsigmoid(2.0f * accH[nt][r]), -1.0f);   // tanh
                float hn = Z[nt][r] * Hold[nt][r] + (1.f - Z[nt][r]) * ht;
                Hold[nt][r] = hn;
                Hw[(q * 4 + r) * 72 + ((nt * 16 + m) ^ wsw)] = (_Float16)hn;
            }
        }
        __threadfence_block();
        aH0 = *(const v8h*)Ard;          // reused next step's Z/R
        aH1 = *(const v8h*)(Ard + 32);

        // ---- output: relu(Hn) @ lin + lin_b ----
        const v8h zz{};
        v8h r0 = __builtin_elementwise_max(aH0, zz);
        v8h r1 = __builtin_elementwise_max(aH1, zz);
        v4f accO = {linbv, linbv, linbv, linbv};
        accO = __builtin_amdgcn_mfma_f32_16x16x32_f16(r0, linB0, accO, 0, 0, 0);
        accO = __builtin_amdgcn_mfma_f32_16x16x32_f16(r1, linB1, accO, 0, 0, 0);
        #pragma unroll
        for (int r = 0; r < 4; ++r)      // C row q*4+r -> (n0, b=r), col m
            op[(size_t)r * (TSTEPS * NN * 16)] = accO[r];
        op += NN * 16;                   // advance t
    }
}

// ---------------- launch ----------------

extern "C" void kernel_launch(void* const* d_in, const int* in_sizes, int n_in,
                              void* d_out, int out_size, void* d_ws, size_t ws_size,
                              hipStream_t stream) {
    const float* x   = (const float*)d_in[0];
    const int*   ei  = (const int*)d_in[1];
    const float* ew  = (const float*)d_in[2];
    const float* Wz  = (const float*)d_in[3];
    const float* bz  = (const float*)d_in[4];
    const float* Wr  = (const float*)d_in[5];
    const float* br  = (const float*)d_in[6];
    const float* Wh  = (const float*)d_in[7];
    const float* bh  = (const float*)d_in[8];
    const float* Lz  = (const float*)d_in[9];
    const float* Lz_b= (const float*)d_in[10];
    const float* Lr  = (const float*)d_in[11];
    const float* Lr_b= (const float*)d_in[12];
    const float* Lh  = (const float*)d_in[13];
    const float* Lh_b= (const float*)d_in[14];
    const float* lw  = (const float*)d_in[15];
    const float* lb  = (const float*)d_in[16];
    float* out = (float*)d_out;

    char* ws = (char*)d_ws;
    size_t off = 0;
    auto alloc = [&](size_t bytes) -> char* {
        char* p = ws + off;
        off += (bytes + 15) & ~(size_t)15;
        return p;
    };
    _Float16* xAll = (_Float16*)alloc((size_t)XTN * 2);
    float* PP      = (float*)alloc(13904 * 4);
    int2*  bucket  = (int2*) alloc((size_t)NN * CAP * 8);
    int*   cnt     = (int*)  alloc(NN * 4);
    float* dinv    = (float*)alloc(NN * 4);

    const int* srcp = ei;
    const int* dstp = ei + NE;

    hipMemsetAsync(cnt, 0, NN * sizeof(int), stream);
    scatter_kernel<<<(NE + 255) / 256, 256, 0, stream>>>(srcp, dstp, ew, cnt, bucket,
                                                         Wz, bz, Wr, br, Wh, bh,
                                                         Lz, Lz_b, Lr, Lr_b, Lh, Lh_b,
                                                         lw, lb, PP);
    prep_kernel<<<(NN + 255) / 256, 256, 0, stream>>>(x, cnt, bucket, dinv, xAll);
    fused_kernel<<<NN / 16, 256, 0, stream>>>(xAll, bucket, cnt, dinv, PP, out);
}